// Round 1
// baseline (91.289 us; speedup 1.0000x reference)
//
#include <hip/hip_runtime.h>
#include <math.h>

#define NPAIRS  262144
#define D4      32                  // 128 floats = 32 float4 per row
#define TPB     256
#define NBLK    1024                // 4 blocks/CU on 256 CUs: one full pass
#define GPB     (TPB / 32)          // 8 groups per block
#define NGROUPS (NBLK * GPB)        // 8192
#define PPG     (NPAIRS / NGROUPS)  // 32 pairs per group per list

// 32-lane group per pair; lane l holds float4 #l of each row (512B coalesced).
//
// Each group takes 32 CONSECUTIVE pairs from each list. Its 32 int2 indices
// (256 B) are preloaded with ONE coalesced int2-per-lane load; per-iteration
// (i,j) come from __shfl broadcast. Consecutive pos pairs share i (nonzero
// row-major runs of ~63) so the a-row stays hot in L1.
//
// Pos: squared distance is separable -> private partials, ONE butterfly.
//
// Neg (NEW): per-pair butterfly (5 dependent ds_bpermute + 1 sqrt PER PAIR)
// replaced by a reduce-scatter transpose over the whole 32-pair batch:
//   - keep s[0..31] per-pair partials in registers
//   - 5 fold stages (xor 16,8,4,2,1) = 31 shfls TOTAL (~1/pair, each stage's
//     shfls independent -> latency 5*~40cy total, not per-pair)
//   - lane l ends with the full distance^2 of pair l -> ONE vector sqrt/relu
//     for all 32 pairs instead of 32 serialized ones.
//
// Reduction: per-block partials to d_ws + finalize kernel. R2/R3 lesson:
// 2048-block atomicAdd to the SAME two addresses serializes at the TCC
// (~25us tail) -- never again.
__global__ __launch_bounds__(TPB, 4) void pair_kernel(
    const float* __restrict__ X,
    const int2*  __restrict__ pos_p,   // pos_idx as int2 stream
    const int2*  __restrict__ neg_p,   // neg_idx as int2 stream
    const float* __restrict__ h_bias,
    float* __restrict__ partials)
{
    const int lane  = threadIdx.x & 31;
    const int group = threadIdx.x >> 5;
    const int gid   = (blockIdx.x * TPB + threadIdx.x) >> 5;

    const float4* __restrict__ X4 = (const float4*)X;

    // numerically stable softplus(h_bias)
    const float hb   = h_bias[0];
    const float bias = fmaxf(hb, 0.0f) + log1pf(expf(-fabsf(hb)));

    // Preload this group's 32 pairs from each list: lane t holds pair t's (i,j).
    const int2 pp = pos_p[gid * 32 + lane];
    const int2 np = neg_p[gid * 32 + lane];

    // ---------------- positive pairs: separable, no per-pair reduce --------
    float posAcc = 0.0f;
    #pragma unroll
    for (int t = 0; t < PPG; ++t) {
        const int i = __shfl(pp.x, t, 32);
        const int j = __shfl(pp.y, t, 32);
        const float4 a = X4[i * D4 + lane];
        const float4 b = X4[j * D4 + lane];
        float d;
        d = a.x - b.x; posAcc = fmaf(d, d, posAcc);
        d = a.y - b.y; posAcc = fmaf(d, d, posAcc);
        d = a.z - b.z; posAcc = fmaf(d, d, posAcc);
        d = a.w - b.w; posAcc = fmaf(d, d, posAcc);
    }
    #pragma unroll
    for (int m = 16; m > 0; m >>= 1) posAcc += __shfl_xor(posAcc, m, 32);

    // ---------------- negative pairs: batched transpose reduce -------------
    float s[PPG];
    #pragma unroll
    for (int t = 0; t < PPG; ++t) {
        const int i = __shfl(np.x, t, 32);
        const int j = __shfl(np.y, t, 32);
        const float4 a = X4[i * D4 + lane];
        const float4 b = X4[j * D4 + lane];
        float d, acc = 0.0f;
        d = a.x - b.x; acc = fmaf(d, d, acc);
        d = a.y - b.y; acc = fmaf(d, d, acc);
        d = a.z - b.z; acc = fmaf(d, d, acc);
        d = a.w - b.w; acc = fmaf(d, d, acc);
        s[t] = acc;
    }
    // Reduce-scatter: after 5 fold stages, lane l holds the full lane-sum of
    // pair l. Each stage: keep the half this lane's side owns, send the other
    // half to the partner, add what the partner sends back.
    #pragma unroll
    for (int t = 0; t < 16; ++t) {
        const float send = (lane & 16) ? s[t]      : s[t + 16];
        const float keep = (lane & 16) ? s[t + 16] : s[t];
        s[t] = keep + __shfl_xor(send, 16, 32);
    }
    #pragma unroll
    for (int t = 0; t < 8; ++t) {
        const float send = (lane & 8) ? s[t]     : s[t + 8];
        const float keep = (lane & 8) ? s[t + 8] : s[t];
        s[t] = keep + __shfl_xor(send, 8, 32);
    }
    #pragma unroll
    for (int t = 0; t < 4; ++t) {
        const float send = (lane & 4) ? s[t]     : s[t + 4];
        const float keep = (lane & 4) ? s[t + 4] : s[t];
        s[t] = keep + __shfl_xor(send, 4, 32);
    }
    #pragma unroll
    for (int t = 0; t < 2; ++t) {
        const float send = (lane & 2) ? s[t]     : s[t + 2];
        const float keep = (lane & 2) ? s[t + 2] : s[t];
        s[t] = keep + __shfl_xor(send, 2, 32);
    }
    {
        const float send = (lane & 1) ? s[0] : s[1];
        const float keep = (lane & 1) ? s[1] : s[0];
        s[0] = keep + __shfl_xor(send, 1, 32);
    }
    // s[0] on lane l = ||x_i - x_j||^2 of neg pair l (unique per lane).
    const float r = fmaxf(bias - sqrtf(s[0]), 0.0f);
    float negAcc = r * r;
    #pragma unroll
    for (int m = 16; m > 0; m >>= 1) negAcc += __shfl_xor(negAcc, m, 32);

    __shared__ float sp[GPB], sn[GPB];
    if (lane == 0) { sp[group] = posAcc; sn[group] = negAcc; }
    __syncthreads();
    if (threadIdx.x == 0) {
        float P = 0.f, Nn = 0.f;
        #pragma unroll
        for (int g = 0; g < GPB; ++g) { P += sp[g]; Nn += sn[g]; }
        partials[2 * blockIdx.x]     = P;
        partials[2 * blockIdx.x + 1] = Nn;
    }
}

__global__ __launch_bounds__(TPB) void finalize_kernel(
    const float* __restrict__ partials, float* __restrict__ out)
{
    __shared__ float sp[TPB], sn[TPB];
    float p = 0.0f, n = 0.0f;
    for (int b = threadIdx.x; b < NBLK; b += TPB) {
        p += partials[2 * b];
        n += partials[2 * b + 1];
    }
    sp[threadIdx.x] = p; sn[threadIdx.x] = n;
    __syncthreads();
    for (int s = TPB / 2; s > 0; s >>= 1) {
        if ((int)threadIdx.x < s) {
            sp[threadIdx.x] += sp[threadIdx.x + s];
            sn[threadIdx.x] += sn[threadIdx.x + s];
        }
        __syncthreads();
    }
    if (threadIdx.x == 0) {
        out[0] = 0.5f * sp[0] / (float)NPAIRS;
        out[1] = 0.5f * sn[0] / (float)NPAIRS;
    }
}

extern "C" void kernel_launch(void* const* d_in, const int* in_sizes, int n_in,
                              void* d_out, int out_size, void* d_ws, size_t ws_size,
                              hipStream_t stream) {
    const float* X      = (const float*)d_in[0];
    // d_in[1] = scores (unused), d_in[3] = labels (unused)
    const float* h_bias = (const float*)d_in[2];
    const int2*  pos_p  = (const int2*)d_in[4];
    const int2*  neg_p  = (const int2*)d_in[5];
    float*       out    = (float*)d_out;
    float*       partials = (float*)d_ws;   // 1024*2 floats, fully written by pair_kernel

    pair_kernel<<<NBLK, TPB, 0, stream>>>(X, pos_p, neg_p, h_bias, partials);
    finalize_kernel<<<1, TPB, 0, stream>>>(partials, out);
}

// Round 2
// 87.167 us; speedup vs baseline: 1.0473x; 1.0473x over previous
//
#include <hip/hip_runtime.h>
#include <math.h>

#define NPAIRS  262144
#define D4      32                  // 128 floats = 32 float4 per row
#define TPB     256
#define NBLK    2048
#define GPB     (TPB / 32)          // 8 groups per block
#define NGROUPS (NBLK * GPB)        // 16384
#define PPG     (NPAIRS / NGROUPS)  // 16 pairs per group per list

// 32-lane group per pair; lane l holds float4 #l of each row (512B coalesced).
//
// R1 post-mortem: cutting shfl/sqrt count was NULL -> kernel is NOT
// VALU-bound. Cycle budget (96k cy/SIMD / 256 iters) = ~375 cy/iter =
// two serialized ~190cy L2-hit loads -> LOAD-LATENCY bound, MLP-starved.
// R2: register pressure down (s[16] not s[32]), occupancy up
// (__launch_bounds__(256,6): ~84 VGPR cap -> 6 waves/SIMD = 24 waves/CU,
// +50% loads in flight). Must-live state ~30 regs, so no spill expected.
//
// Neg reduction: transposed reduce-scatter (R1, verified-correct pattern):
// fold 16 per-pair partials across lanes in 4 stages (xor 8,4,2,1), then one
// cross-half add -> lane l holds pair (l&15)'s full distance^2; ONE vector
// sqrt for 16 pairs. Lane sum of r^2 counts each pair twice -> x0.5.
//
// Reduction: per-block partials to d_ws + finalize kernel. R2/R3 lesson
// (prev session): 2048-block atomicAdd to the SAME two addresses serializes
// at the TCC (~25us tail) -- never again.
__global__ __launch_bounds__(TPB, 6) void pair_kernel(
    const float* __restrict__ X,
    const int2*  __restrict__ pos_p,   // pos_idx as int2 stream
    const int2*  __restrict__ neg_p,   // neg_idx as int2 stream
    const float* __restrict__ h_bias,
    float* __restrict__ partials)
{
    const int lane  = threadIdx.x & 31;
    const int group = threadIdx.x >> 5;
    const int gid   = (blockIdx.x * TPB + threadIdx.x) >> 5;

    const float4* __restrict__ X4 = (const float4*)X;

    // numerically stable softplus(h_bias)
    const float hb   = h_bias[0];
    const float bias = fmaxf(hb, 0.0f) + log1pf(expf(-fabsf(hb)));

    // Preload this group's 16 pairs from each list (lanes 16..31 duplicate
    // lanes 0..15 -- same cacheline, broadcast reads only lanes 0..15).
    const int2 pp = pos_p[gid * PPG + (lane & (PPG - 1))];
    const int2 np = neg_p[gid * PPG + (lane & (PPG - 1))];

    // ---------------- positive pairs: separable, no per-pair reduce --------
    float posAcc = 0.0f;
    #pragma unroll
    for (int t = 0; t < PPG; ++t) {
        const int i = __shfl(pp.x, t, 32);
        const int j = __shfl(pp.y, t, 32);
        const float4 a = X4[i * D4 + lane];
        const float4 b = X4[j * D4 + lane];
        float d;
        d = a.x - b.x; posAcc = fmaf(d, d, posAcc);
        d = a.y - b.y; posAcc = fmaf(d, d, posAcc);
        d = a.z - b.z; posAcc = fmaf(d, d, posAcc);
        d = a.w - b.w; posAcc = fmaf(d, d, posAcc);
    }
    #pragma unroll
    for (int m = 16; m > 0; m >>= 1) posAcc += __shfl_xor(posAcc, m, 32);

    // ---------------- negative pairs: batched transpose reduce -------------
    float s[PPG];
    #pragma unroll
    for (int t = 0; t < PPG; ++t) {
        const int i = __shfl(np.x, t, 32);
        const int j = __shfl(np.y, t, 32);
        const float4 a = X4[i * D4 + lane];
        const float4 b = X4[j * D4 + lane];
        float d, acc = 0.0f;
        d = a.x - b.x; acc = fmaf(d, d, acc);
        d = a.y - b.y; acc = fmaf(d, d, acc);
        d = a.z - b.z; acc = fmaf(d, d, acc);
        d = a.w - b.w; acc = fmaf(d, d, acc);
        s[t] = acc;
    }
    // Reduce-scatter within each 16-lane half: 4 fold stages; lane l ends
    // with pair (l&15)'s sum over its half; then one cross-half add.
    #pragma unroll
    for (int t = 0; t < 8; ++t) {
        const float send = (lane & 8) ? s[t]     : s[t + 8];
        const float keep = (lane & 8) ? s[t + 8] : s[t];
        s[t] = keep + __shfl_xor(send, 8, 32);
    }
    #pragma unroll
    for (int t = 0; t < 4; ++t) {
        const float send = (lane & 4) ? s[t]     : s[t + 4];
        const float keep = (lane & 4) ? s[t + 4] : s[t];
        s[t] = keep + __shfl_xor(send, 4, 32);
    }
    #pragma unroll
    for (int t = 0; t < 2; ++t) {
        const float send = (lane & 2) ? s[t]     : s[t + 2];
        const float keep = (lane & 2) ? s[t + 2] : s[t];
        s[t] = keep + __shfl_xor(send, 2, 32);
    }
    {
        const float send = (lane & 1) ? s[0] : s[1];
        const float keep = (lane & 1) ? s[1] : s[0];
        s[0] = keep + __shfl_xor(send, 1, 32);
    }
    s[0] += __shfl_xor(s[0], 16, 32);   // cross-half: full distance^2
    // lane l and l+16 both hold pair (l&15) -> each pair counted twice below.
    const float r = fmaxf(bias - sqrtf(s[0]), 0.0f);
    float negAcc = r * r;
    #pragma unroll
    for (int m = 16; m > 0; m >>= 1) negAcc += __shfl_xor(negAcc, m, 32);
    negAcc *= 0.5f;                     // undo the 2x pair duplication

    __shared__ float sp[GPB], sn[GPB];
    if (lane == 0) { sp[group] = posAcc; sn[group] = negAcc; }
    __syncthreads();
    if (threadIdx.x == 0) {
        float P = 0.f, Nn = 0.f;
        #pragma unroll
        for (int g = 0; g < GPB; ++g) { P += sp[g]; Nn += sn[g]; }
        partials[2 * blockIdx.x]     = P;
        partials[2 * blockIdx.x + 1] = Nn;
    }
}

__global__ __launch_bounds__(TPB) void finalize_kernel(
    const float* __restrict__ partials, float* __restrict__ out)
{
    __shared__ float sp[TPB], sn[TPB];
    float p = 0.0f, n = 0.0f;
    for (int b = threadIdx.x; b < NBLK; b += TPB) {
        p += partials[2 * b];
        n += partials[2 * b + 1];
    }
    sp[threadIdx.x] = p; sn[threadIdx.x] = n;
    __syncthreads();
    for (int s = TPB / 2; s > 0; s >>= 1) {
        if ((int)threadIdx.x < s) {
            sp[threadIdx.x] += sp[threadIdx.x + s];
            sn[threadIdx.x] += sn[threadIdx.x + s];
        }
        __syncthreads();
    }
    if (threadIdx.x == 0) {
        out[0] = 0.5f * sp[0] / (float)NPAIRS;
        out[1] = 0.5f * sn[0] / (float)NPAIRS;
    }
}

extern "C" void kernel_launch(void* const* d_in, const int* in_sizes, int n_in,
                              void* d_out, int out_size, void* d_ws, size_t ws_size,
                              hipStream_t stream) {
    const float* X      = (const float*)d_in[0];
    // d_in[1] = scores (unused), d_in[3] = labels (unused)
    const float* h_bias = (const float*)d_in[2];
    const int2*  pos_p  = (const int2*)d_in[4];
    const int2*  neg_p  = (const int2*)d_in[5];
    float*       out    = (float*)d_out;
    float*       partials = (float*)d_ws;   // 2048*2 floats, fully written by pair_kernel

    pair_kernel<<<NBLK, TPB, 0, stream>>>(X, pos_p, neg_p, h_bias, partials);
    finalize_kernel<<<1, TPB, 0, stream>>>(partials, out);
}